// Round 1
// 898.410 us; speedup vs baseline: 1.0096x; 1.0096x over previous
//
#include <hip/hip_runtime.h>
#include <stdint.h>
#include <stddef.h>

// Problem constants (B=2, S=2048, D_MODEL=1024, H=16, Dh=64).
// I/O dtype: fp32 (per reference). Internal compute: bf16 MFMA + fp32 accum.
#define D_MODEL 1024
#define NHEADS  16
#define HDIM    64
#define BB      2
#define SSEQ    2048

using bf16x8 = __attribute__((ext_vector_type(8))) short;  // 8 bf16 (4 VGPRs)
using f32x4  = __attribute__((ext_vector_type(4))) float;  // MFMA accumulator
using s16x4  = __attribute__((ext_vector_type(4))) short;

static __device__ __forceinline__ float b2f(short s) {
  union { float f; unsigned u; } v;
  v.u = ((unsigned)(unsigned short)s) << 16;
  return v.f;
}
static __device__ __forceinline__ short f2b(float f) {
  union { float f; unsigned u; } v;
  v.f = f;
  unsigned r = v.u + 0x7fffu + ((v.u >> 16) & 1u);  // RNE
  return (short)(r >> 16);
}

// async global->LDS, 16B per lane; LDS dest = wave-uniform base + lane*16
static __device__ __forceinline__ void gload16(const void* g, void* l) {
  __builtin_amdgcn_global_load_lds(
      (const __attribute__((address_space(1))) unsigned int*)g,
      (__attribute__((address_space(3))) unsigned int*)l, 16, 0, 0);
}

// ---------------------------------------------------------------------------
// fp32 -> bf16 conversion (grid-stride, float4 loads, 8B stores)
// ---------------------------------------------------------------------------
__global__ __launch_bounds__(256) void k_cvt(const float* __restrict__ src,
                                             short* __restrict__ dst, int n4) {
  int i = blockIdx.x * blockDim.x + threadIdx.x;
  const int stride = gridDim.x * blockDim.x;
  for (; i < n4; i += stride) {
    const float4 v = ((const float4*)src)[i];
    s16x4 o;
    o[0] = f2b(v.x); o[1] = f2b(v.y); o[2] = f2b(v.z); o[3] = f2b(v.w);
    ((s16x4*)dst)[i] = o;
  }
}

// ---------------------------------------------------------------------------
// C[M,N] = A[M,K] @ W[N,K]^T   (bf16 in, fp32 accum; out bf16 or fp32)
// 128x128 tile, BK=32, 256 threads (4 waves in 2x2), m97-style staging.
// ---------------------------------------------------------------------------
template <bool F32OUT>
static __device__ __forceinline__ void gemm_bt_dev(
    const short* __restrict__ A, const short* __restrict__ W, void* __restrict__ Cv,
    int N, int K) {
  __shared__ short sA[128 * 32];
  __shared__ short sB[128 * 32];

  const int t  = threadIdx.x;
  const int l  = t & 63;
  const int w  = t >> 6;
  const int wm = w >> 1, wn = w & 1;
  const int g  = l >> 4, lr = l & 15;
  const int m0 = blockIdx.y * 128;
  const int n0 = blockIdx.x * 128;

  f32x4 acc[4][4];
#pragma unroll
  for (int i = 0; i < 4; ++i)
#pragma unroll
    for (int j = 0; j < 4; ++j) {
      acc[i][j][0] = 0.f; acc[i][j][1] = 0.f;
      acc[i][j][2] = 0.f; acc[i][j][3] = 0.f;
    }

  // staging: chunk t (16B) = tile row t/4, cols (t%4)*8 .. +8; thread t owns
  // chunks t and t+256; LDS offset of chunk i is i*16B (row-major [128][32]).
  const int r0 = t >> 2;
  const int c0 = (t & 3) * 8;
  const short* ga0 = A + (size_t)(m0 + r0) * K + c0;
  const short* ga1 = A + (size_t)(m0 + 64 + r0) * K + c0;
  const short* gb0 = W + (size_t)(n0 + r0) * K + c0;
  const short* gb1 = W + (size_t)(n0 + 64 + r0) * K + c0;
  short* la0 = &sA[(t & ~63) * 8];
  short* la1 = la0 + 256 * 8;
  short* lb0 = &sB[(t & ~63) * 8];
  short* lb1 = lb0 + 256 * 8;

  for (int k0 = 0; k0 < K; k0 += 32) {
    __syncthreads();  // WAR: previous iter's fragment reads done
    gload16(ga0 + k0, la0);
    gload16(ga1 + k0, la1);
    gload16(gb0 + k0, lb0);
    gload16(gb1 + k0, lb1);
    __syncthreads();  // drains vmcnt: staged tile visible

    bf16x8 af[4], bfr[4];
#pragma unroll
    for (int i = 0; i < 4; ++i)
      af[i] = *(const bf16x8*)&sA[(wm * 64 + i * 16 + lr) * 32 + g * 8];
#pragma unroll
    for (int i = 0; i < 4; ++i)
      bfr[i] = *(const bf16x8*)&sB[(wn * 64 + i * 16 + lr) * 32 + g * 8];
#pragma unroll
    for (int i = 0; i < 4; ++i)
#pragma unroll
      for (int j = 0; j < 4; ++j)
        acc[i][j] = __builtin_amdgcn_mfma_f32_16x16x32_bf16(af[i], bfr[j],
                                                            acc[i][j], 0, 0, 0);
  }

  // epilogue: D row=(lane>>4)*4+reg, col=lane&15  [verified C/D layout]
#pragma unroll
  for (int i = 0; i < 4; ++i)
#pragma unroll
    for (int j = 0; j < 4; ++j)
#pragma unroll
      for (int rr = 0; rr < 4; ++rr) {
        const int row = m0 + wm * 64 + i * 16 + g * 4 + rr;
        const int col = n0 + wn * 64 + j * 16 + lr;
        if (F32OUT)
          ((float*)Cv)[(size_t)row * N + col] = acc[i][j][rr];
        else
          ((short*)Cv)[(size_t)row * N + col] = f2b(acc[i][j][rr]);
      }
}

__global__ __launch_bounds__(256) void k_gemm_f32out(
    const short* __restrict__ A, const short* __restrict__ W,
    float* __restrict__ C, int N, int K) {
  gemm_bt_dev<true>(A, W, C, N, K);
}

__global__ __launch_bounds__(256) void k_gemm_qkv(
    const short* __restrict__ q, const short* __restrict__ k,
    const short* __restrict__ v, const short* __restrict__ wq,
    const short* __restrict__ wk, const short* __restrict__ wv,
    short* __restrict__ Qb, short* __restrict__ Kb, short* __restrict__ Vb) {
  const short *A, *W;
  short* C;
  if (blockIdx.z == 0)      { A = q; W = wq; C = Qb; }
  else if (blockIdx.z == 1) { A = k; W = wk; C = Kb; }
  else                      { A = v; W = wv; C = Vb; }
  gemm_bt_dev<false>(A, W, C, D_MODEL, D_MODEL);
}

// ---------------------------------------------------------------------------
// V[b,s,h*64+d] -> Vt[b,h,d,s]  (64x64 LDS tiles, pad 66 to spread banks)
// ---------------------------------------------------------------------------
__global__ __launch_bounds__(256) void k_transpose_v(
    const short* __restrict__ Vb, short* __restrict__ Vt) {
  __shared__ short tile[64][66];
  const int bh = blockIdx.x;            // b*16+h
  const int b = bh >> 4, h = bh & 15;
  const int s0 = blockIdx.y * 64;
  const int t = threadIdx.x;
#pragma unroll
  for (int i = 0; i < 16; ++i) {
    int e = t + i * 256;
    int si = e >> 6, dj = e & 63;
    tile[si][dj] = Vb[((size_t)b * SSEQ + s0 + si) * D_MODEL + h * HDIM + dj];
  }
  __syncthreads();
#pragma unroll
  for (int i = 0; i < 16; ++i) {
    int e = t + i * 256;
    int dj = e >> 6, si = e & 63;
    Vt[((size_t)bh * HDIM + dj) * SSEQ + s0 + si] = tile[si][dj];
  }
}

// ---------------------------------------------------------------------------
// Fused attention: per block = (b,h, 16 q-rows), 512 threads (8 waves).
//   scores = Q Kt / 8 (MFMA) -> LDS (bf16, xor-swizzled 16B chunks)
//   softmax (32 lanes per row, shuffle reduce)
//   P -> attn output (fp32) and back to LDS (bf16)
//   context = P @ V (MFMA, B-operand from Vt); K-dim split across wave
//   halves, f32x4 partials reduced through a 4 KB LDS buffer.
// LDS 68 KB -> 2 blocks/CU * 8 waves = 16 waves/CU (50% occupancy; the
// 256-thread version sat at 23% and was latency-bound on every pipe).
// ---------------------------------------------------------------------------
__global__ __launch_bounds__(512) void k_attn(
    const short* __restrict__ Qb, const short* __restrict__ Kb,
    const short* __restrict__ Vt, float* __restrict__ attnO,
    short* __restrict__ ctx) {
  __shared__ short S[16 * SSEQ];   // 64 KB score/P tile
  __shared__ f32x4 red[4 * 64];    // 4 KB PV partial-sum buffer
  const int t = threadIdx.x;
  const int l = t & 63, w = t >> 6;       // 8 waves
  const int g = l >> 4, lr = l & 15;
  const int bh = blockIdx.y;  // 0..31
  const int b = bh >> 4, h = bh & 15;
  const int q0 = blockIdx.x * 16;

  // Q fragments (A-operand): lane holds Q[q0+lr][g*8 .. +8] (+32 for step 2)
  const size_t qoff = ((size_t)b * SSEQ + q0 + lr) * D_MODEL + h * HDIM;
  const bf16x8 aq0 = *(const bf16x8*)&Qb[qoff + g * 8];
  const bf16x8 aq1 = *(const bf16x8*)&Qb[qoff + 32 + g * 8];

  const short* Kh = Kb + (size_t)b * SSEQ * D_MODEL + h * HDIM;

  // ---- QK^T: wave w covers n-tiles [w*16, w*16+16) ----
  for (int nt = 0; nt < 16; ++nt) {
    const int n0 = (w * 16 + nt) * 16;
    const short* krow = Kh + (size_t)(n0 + lr) * D_MODEL;
    const bf16x8 bk0 = *(const bf16x8*)&krow[g * 8];
    const bf16x8 bk1 = *(const bf16x8*)&krow[32 + g * 8];
    f32x4 acc;
    acc[0] = 0.f; acc[1] = 0.f; acc[2] = 0.f; acc[3] = 0.f;
    acc = __builtin_amdgcn_mfma_f32_16x16x32_bf16(aq0, bk0, acc, 0, 0, 0);
    acc = __builtin_amdgcn_mfma_f32_16x16x32_bf16(aq1, bk1, acc, 0, 0, 0);
#pragma unroll
    for (int rr = 0; rr < 4; ++rr) {
      const int row = g * 4 + rr;         // q-row in tile
      const int col = n0 + lr;            // key index
      const int pc = (col >> 3) ^ (row & 7);
      S[row * SSEQ + pc * 8 + (col & 7)] = f2b(acc[rr] * 0.125f);
    }
  }
  __syncthreads();

  // ---- softmax: row r handled by 32 lanes (j), 8 chunks of 8 each ----
  const int r = t >> 5, j = t & 31;
  float mx = -1e30f;
  for (int i = 0; i < 8; ++i) {
    const int c = j + (i << 5);
    const int pc = c ^ (r & 7);
    const bf16x8 v = *(const bf16x8*)&S[r * SSEQ + pc * 8];
#pragma unroll
    for (int e = 0; e < 8; ++e) mx = fmaxf(mx, b2f(v[e]));
  }
#pragma unroll
  for (int mask = 1; mask < 32; mask <<= 1)
    mx = fmaxf(mx, __shfl_xor(mx, mask, 64));

  float sum = 0.f;
  for (int i = 0; i < 8; ++i) {
    const int c = j + (i << 5);
    const int pc = c ^ (r & 7);
    const bf16x8 v = *(const bf16x8*)&S[r * SSEQ + pc * 8];
#pragma unroll
    for (int e = 0; e < 8; ++e) sum += __expf(b2f(v[e]) - mx);
  }
#pragma unroll
  for (int mask = 1; mask < 32; mask <<= 1) sum += __shfl_xor(sum, mask, 64);
  const float inv = 1.f / sum;

  float* arow = attnO + ((size_t)bh * SSEQ + q0 + r) * SSEQ;
  for (int i = 0; i < 8; ++i) {
    const int c = j + (i << 5);
    const int pc = c ^ (r & 7);
    const bf16x8 v = *(const bf16x8*)&S[r * SSEQ + pc * 8];
    bf16x8 p;
#pragma unroll
    for (int e = 0; e < 8; ++e) {
      const float pe = __expf(b2f(v[e]) - mx) * inv;
      p[e] = f2b(pe);
      arow[(size_t)c * 8 + e] = pe;               // attn_weights (fp32)
    }
    *(bf16x8*)&S[r * SSEQ + pc * 8] = p;          // for PV
  }
  __syncthreads();

  // ---- PV: wave w -> d-tile d0=(w&3)*16, K-half kh=w>>2 (1024 each) ----
  const short* Vh = Vt + (size_t)bh * HDIM * SSEQ;
  const int d0 = (w & 3) * 16;
  const int kh = w >> 2;
  f32x4 acc;
  acc[0] = 0.f; acc[1] = 0.f; acc[2] = 0.f; acc[3] = 0.f;
  const int sbeg = kh * (SSEQ / 2);
  for (int s0 = sbeg; s0 < sbeg + SSEQ / 2; s0 += 32) {
    const int pc = ((s0 >> 3) + g) ^ (lr & 7);
    const bf16x8 ap = *(const bf16x8*)&S[lr * SSEQ + pc * 8];
    const bf16x8 bv =
        *(const bf16x8*)&Vh[(size_t)(d0 + lr) * SSEQ + s0 + g * 8];
    acc = __builtin_amdgcn_mfma_f32_16x16x32_bf16(ap, bv, acc, 0, 0, 0);
  }
  if (kh == 1) red[(w & 3) * 64 + l] = acc;
  __syncthreads();
  if (kh == 0) {
    const f32x4 o = red[(w & 3) * 64 + l];
    acc[0] += o[0]; acc[1] += o[1]; acc[2] += o[2]; acc[3] += o[3];
#pragma unroll
    for (int rr = 0; rr < 4; ++rr) {
      const int qr = q0 + g * 4 + rr;
      ctx[((size_t)b * SSEQ + qr) * D_MODEL + h * HDIM + d0 + lr] =
          f2b(acc[rr]);
    }
  }
}

// ---------------------------------------------------------------------------
extern "C" void kernel_launch(void* const* d_in, const int* in_sizes, int n_in,
                              void* d_out, int out_size, void* d_ws,
                              size_t ws_size, hipStream_t stream) {
  const float* qf  = (const float*)d_in[0];
  const float* kf  = (const float*)d_in[1];
  const float* vf  = (const float*)d_in[2];
  const float* wqf = (const float*)d_in[3];
  const float* wkf = (const float*)d_in[4];
  const float* wvf = (const float*)d_in[5];
  const float* wof = (const float*)d_in[6];

  float* out  = (float*)d_out;                       // [2,2048,1024]
  float* attn = out + (size_t)BB * SSEQ * D_MODEL;   // [2,16,2048,2048]

  const size_t NTOK = (size_t)BB * SSEQ;             // 4096
  const size_t XN = NTOK * D_MODEL;                  // 4M elements
  const size_t WN = (size_t)D_MODEL * D_MODEL;       // 1M elements

  short* qb  = (short*)d_ws;       // bf16 copies of inputs
  short* kb  = qb + XN;
  short* vb  = kb + XN;
  short* wqb = vb + XN;
  short* wkb = wqb + WN;
  short* wvb = wkb + WN;
  short* wob = wvb + WN;
  short* Qb  = wob + WN;           // projection results
  short* Kb  = Qb + XN;
  short* Vb  = Kb + XN;
  short* Vt  = Vb + XN;
  short* ctx = Vt + XN;            // total 72 MB

  // 0) fp32 -> bf16 conversions
  k_cvt<<<512, 256, 0, stream>>>(qf, qb, (int)(XN / 4));
  k_cvt<<<512, 256, 0, stream>>>(kf, kb, (int)(XN / 4));
  k_cvt<<<512, 256, 0, stream>>>(vf, vb, (int)(XN / 4));
  k_cvt<<<256, 256, 0, stream>>>(wqf, wqb, (int)(WN / 4));
  k_cvt<<<256, 256, 0, stream>>>(wkf, wkb, (int)(WN / 4));
  k_cvt<<<256, 256, 0, stream>>>(wvf, wvb, (int)(WN / 4));
  k_cvt<<<256, 256, 0, stream>>>(wof, wob, (int)(WN / 4));

  // 1) Q/K/V projections: x @ W^T
  k_gemm_qkv<<<dim3(D_MODEL / 128, NTOK / 128, 3), 256, 0, stream>>>(
      qb, kb, vb, wqb, wkb, wvb, Qb, Kb, Vb);
  // 2) V -> Vt[b,h,d,s]
  k_transpose_v<<<dim3(BB * NHEADS, SSEQ / 64), 256, 0, stream>>>(Vb, Vt);
  // 3) fused attention (+ attn_weights output, fp32)
  k_attn<<<dim3(SSEQ / 16, BB * NHEADS), 512, 0, stream>>>(Qb, Kb, Vt, attn,
                                                           ctx);
  // 4) output projection: ctx @ Wo^T (fp32 out)
  k_gemm_f32out<<<dim3(D_MODEL / 128, NTOK / 128), 256, 0, stream>>>(
      ctx, wob, out, D_MODEL, D_MODEL);
}

// Round 4
// 885.744 us; speedup vs baseline: 1.0240x; 1.0143x over previous
//
#include <hip/hip_runtime.h>
#include <stdint.h>
#include <stddef.h>

// Problem constants (B=2, S=2048, D_MODEL=1024, H=16, Dh=64).
// I/O dtype: fp32 (per reference). Internal compute: bf16 MFMA + fp32 accum.
#define D_MODEL 1024
#define NHEADS  16
#define HDIM    64
#define BB      2
#define SSEQ    2048

using bf16x8 = __attribute__((ext_vector_type(8))) short;  // 8 bf16 (4 VGPRs)
using f32x4  = __attribute__((ext_vector_type(4))) float;  // MFMA accumulator
using s16x4  = __attribute__((ext_vector_type(4))) short;

static __device__ __forceinline__ float b2f(short s) {
  union { float f; unsigned u; } v;
  v.u = ((unsigned)(unsigned short)s) << 16;
  return v.f;
}
static __device__ __forceinline__ short f2b(float f) {
  union { float f; unsigned u; } v;
  v.f = f;
  unsigned r = v.u + 0x7fffu + ((v.u >> 16) & 1u);  // RNE
  return (short)(r >> 16);
}

// async global->LDS, 16B per lane; LDS dest = wave-uniform base + lane*16
static __device__ __forceinline__ void gload16(const void* g, void* l) {
  __builtin_amdgcn_global_load_lds(
      (const __attribute__((address_space(1))) unsigned int*)g,
      (__attribute__((address_space(3))) unsigned int*)l, 16, 0, 0);
}

// ---------------------------------------------------------------------------
// fp32 -> bf16 conversion (grid-stride, float4 loads, 8B stores)
// ---------------------------------------------------------------------------
__global__ __launch_bounds__(256) void k_cvt(const float* __restrict__ src,
                                             short* __restrict__ dst, int n4) {
  int i = blockIdx.x * blockDim.x + threadIdx.x;
  const int stride = gridDim.x * blockDim.x;
  for (; i < n4; i += stride) {
    const float4 v = ((const float4*)src)[i];
    s16x4 o;
    o[0] = f2b(v.x); o[1] = f2b(v.y); o[2] = f2b(v.z); o[3] = f2b(v.w);
    ((s16x4*)dst)[i] = o;
  }
}

// ---------------------------------------------------------------------------
// C[M,N] = A[M,K] @ W[N,K]^T   (bf16 in, fp32 accum; out bf16 or fp32)
// 128x128 tile, BK=32, 256 threads (4 waves in 2x2), m97-style staging.
// ---------------------------------------------------------------------------
template <bool F32OUT>
static __device__ __forceinline__ void gemm_bt_dev(
    const short* __restrict__ A, const short* __restrict__ W, void* __restrict__ Cv,
    int N, int K) {
  __shared__ short sA[128 * 32];
  __shared__ short sB[128 * 32];

  const int t  = threadIdx.x;
  const int l  = t & 63;
  const int w  = t >> 6;
  const int wm = w >> 1, wn = w & 1;
  const int g  = l >> 4, lr = l & 15;
  const int m0 = blockIdx.y * 128;
  const int n0 = blockIdx.x * 128;

  f32x4 acc[4][4];
#pragma unroll
  for (int i = 0; i < 4; ++i)
#pragma unroll
    for (int j = 0; j < 4; ++j) {
      acc[i][j][0] = 0.f; acc[i][j][1] = 0.f;
      acc[i][j][2] = 0.f; acc[i][j][3] = 0.f;
    }

  // staging: chunk t (16B) = tile row t/4, cols (t%4)*8 .. +8; thread t owns
  // chunks t and t+256; LDS offset of chunk i is i*16B (row-major [128][32]).
  const int r0 = t >> 2;
  const int c0 = (t & 3) * 8;
  const short* ga0 = A + (size_t)(m0 + r0) * K + c0;
  const short* ga1 = A + (size_t)(m0 + 64 + r0) * K + c0;
  const short* gb0 = W + (size_t)(n0 + r0) * K + c0;
  const short* gb1 = W + (size_t)(n0 + 64 + r0) * K + c0;
  short* la0 = &sA[(t & ~63) * 8];
  short* la1 = la0 + 256 * 8;
  short* lb0 = &sB[(t & ~63) * 8];
  short* lb1 = lb0 + 256 * 8;

  for (int k0 = 0; k0 < K; k0 += 32) {
    __syncthreads();  // WAR: previous iter's fragment reads done
    gload16(ga0 + k0, la0);
    gload16(ga1 + k0, la1);
    gload16(gb0 + k0, lb0);
    gload16(gb1 + k0, lb1);
    __syncthreads();  // drains vmcnt: staged tile visible

    bf16x8 af[4], bfr[4];
#pragma unroll
    for (int i = 0; i < 4; ++i)
      af[i] = *(const bf16x8*)&sA[(wm * 64 + i * 16 + lr) * 32 + g * 8];
#pragma unroll
    for (int i = 0; i < 4; ++i)
      bfr[i] = *(const bf16x8*)&sB[(wn * 64 + i * 16 + lr) * 32 + g * 8];
#pragma unroll
    for (int i = 0; i < 4; ++i)
#pragma unroll
      for (int j = 0; j < 4; ++j)
        acc[i][j] = __builtin_amdgcn_mfma_f32_16x16x32_bf16(af[i], bfr[j],
                                                            acc[i][j], 0, 0, 0);
  }

  // epilogue: D row=(lane>>4)*4+reg, col=lane&15  [verified C/D layout]
#pragma unroll
  for (int i = 0; i < 4; ++i)
#pragma unroll
    for (int j = 0; j < 4; ++j)
#pragma unroll
      for (int rr = 0; rr < 4; ++rr) {
        const int row = m0 + wm * 64 + i * 16 + g * 4 + rr;
        const int col = n0 + wn * 64 + j * 16 + lr;
        if (F32OUT)
          ((float*)Cv)[(size_t)row * N + col] = acc[i][j][rr];
        else
          ((short*)Cv)[(size_t)row * N + col] = f2b(acc[i][j][rr]);
      }
}

__global__ __launch_bounds__(256) void k_gemm_f32out(
    const short* __restrict__ A, const short* __restrict__ W,
    float* __restrict__ C, int N, int K) {
  gemm_bt_dev<true>(A, W, C, N, K);
}

__global__ __launch_bounds__(256) void k_gemm_qkv(
    const short* __restrict__ q, const short* __restrict__ k,
    const short* __restrict__ v, const short* __restrict__ wq,
    const short* __restrict__ wk, const short* __restrict__ wv,
    short* __restrict__ Qb, short* __restrict__ Kb, short* __restrict__ Vb) {
  const short *A, *W;
  short* C;
  if (blockIdx.z == 0)      { A = q; W = wq; C = Qb; }
  else if (blockIdx.z == 1) { A = k; W = wk; C = Kb; }
  else                      { A = v; W = wv; C = Vb; }
  gemm_bt_dev<false>(A, W, C, D_MODEL, D_MODEL);
}

// ---------------------------------------------------------------------------
// V[b,s,h*64+d] -> Vt[b,h,d,s]  (64x64 LDS tiles, pad 66 to spread banks)
// ---------------------------------------------------------------------------
__global__ __launch_bounds__(256) void k_transpose_v(
    const short* __restrict__ Vb, short* __restrict__ Vt) {
  __shared__ short tile[64][66];
  const int bh = blockIdx.x;            // b*16+h
  const int b = bh >> 4, h = bh & 15;
  const int s0 = blockIdx.y * 64;
  const int t = threadIdx.x;
#pragma unroll
  for (int i = 0; i < 16; ++i) {
    int e = t + i * 256;
    int si = e >> 6, dj = e & 63;
    tile[si][dj] = Vb[((size_t)b * SSEQ + s0 + si) * D_MODEL + h * HDIM + dj];
  }
  __syncthreads();
#pragma unroll
  for (int i = 0; i < 16; ++i) {
    int e = t + i * 256;
    int dj = e >> 6, si = e & 63;
    Vt[((size_t)bh * HDIM + dj) * SSEQ + s0 + si] = tile[si][dj];
  }
}

// ---------------------------------------------------------------------------
// Fused attention: per block = (b,h, 16 q-rows), 512 threads (8 waves).
// Round-4 = round-2 experiment with exotic constructs removed after two
// container failures (nontemporal-store builtin + partial-unroll pragmas
// dropped; plain float4 stores kept -> still 16B vectorized vs r1 scalar):
//   - row-max FUSED into QK^T (register partial max + shfl reduce + 512B LDS)
//     -> softmax is now 2 S-sweeps (sum, scale+store), was 3.
//   - QK^T batches 2 n-tiles (4 K loads in flight); PV batches 4 steps
//     (4 ds_read_b128 + 4 global loads in flight) before the MFMAs.
//   - XCD-chunked bijective block swizzle: each XCD owns 4 whole (b,h) heads,
//     so each head's 512 KB K+Vt working set stays in its own L2.
// LDS 68.5 KB -> 2 blocks/CU * 8 waves = 16 waves/CU.
// ---------------------------------------------------------------------------
__global__ __launch_bounds__(512) void k_attn(
    const short* __restrict__ Qb, const short* __restrict__ Kb,
    const short* __restrict__ Vt, float* __restrict__ attnO,
    short* __restrict__ ctx) {
  __shared__ short S[16 * SSEQ];    // 64 KB score/P tile
  __shared__ f32x4 red[4 * 64];     // 4 KB PV partial-sum buffer
  __shared__ float rowmax[16][8];   // 512 B per-wave row maxima
  const int t = threadIdx.x;
  const int l = t & 63, w = t >> 6;       // 8 waves
  const int g = l >> 4, lr = l & 15;
  // XCD swizzle: 4096 blocks, XCD = orig%8 -> give each XCD ids [x*512,x*512+512)
  const int orig = blockIdx.x;
  const int id = (orig & 7) * 512 + (orig >> 3);
  const int q0 = (id & 127) * 16;
  const int bh = id >> 7;  // 0..31
  const int b = bh >> 4, h = bh & 15;

  // Q fragments (A-operand): lane holds Q[q0+lr][g*8 .. +8] (+32 for step 2)
  const size_t qoff = ((size_t)b * SSEQ + q0 + lr) * D_MODEL + h * HDIM;
  const bf16x8 aq0 = *(const bf16x8*)&Qb[qoff + g * 8];
  const bf16x8 aq1 = *(const bf16x8*)&Qb[qoff + 32 + g * 8];

  const short* Kh = Kb + (size_t)b * SSEQ * D_MODEL + h * HDIM;

  // ---- QK^T: wave w covers n-tiles [w*16, w*16+16), 2 per iter ----
  f32x4 pmax;
  pmax[0] = -1e30f; pmax[1] = -1e30f; pmax[2] = -1e30f; pmax[3] = -1e30f;
  for (int nt = 0; nt < 16; nt += 2) {
    const int n0a = (w * 16 + nt) * 16;
    const int n0b = n0a + 16;
    const short* kra = Kh + (size_t)(n0a + lr) * D_MODEL;
    const short* krb = Kh + (size_t)(n0b + lr) * D_MODEL;
    const bf16x8 ka0 = *(const bf16x8*)&kra[g * 8];
    const bf16x8 ka1 = *(const bf16x8*)&kra[32 + g * 8];
    const bf16x8 kb0 = *(const bf16x8*)&krb[g * 8];
    const bf16x8 kb1 = *(const bf16x8*)&krb[32 + g * 8];
    f32x4 acca, accb;
    acca[0] = 0.f; acca[1] = 0.f; acca[2] = 0.f; acca[3] = 0.f;
    accb[0] = 0.f; accb[1] = 0.f; accb[2] = 0.f; accb[3] = 0.f;
    acca = __builtin_amdgcn_mfma_f32_16x16x32_bf16(aq0, ka0, acca, 0, 0, 0);
    acca = __builtin_amdgcn_mfma_f32_16x16x32_bf16(aq1, ka1, acca, 0, 0, 0);
    accb = __builtin_amdgcn_mfma_f32_16x16x32_bf16(aq0, kb0, accb, 0, 0, 0);
    accb = __builtin_amdgcn_mfma_f32_16x16x32_bf16(aq1, kb1, accb, 0, 0, 0);
#pragma unroll
    for (int rr = 0; rr < 4; ++rr) {
      const int row = g * 4 + rr;         // q-row in tile
      const float sa = acca[rr] * 0.125f;
      const float sb = accb[rr] * 0.125f;
      pmax[rr] = fmaxf(pmax[rr], fmaxf(sa, sb));
      const int ca = n0a + lr, cb = n0b + lr;
      S[row * SSEQ + (((ca >> 3) ^ (row & 7)) << 3) + (ca & 7)] = f2b(sa);
      S[row * SSEQ + (((cb >> 3) ^ (row & 7)) << 3) + (cb & 7)] = f2b(sb);
    }
  }
  // reduce row-max across the 16 lanes of each g-group (rows g*4..g*4+3)
#pragma unroll
  for (int mask = 1; mask < 16; mask <<= 1)
#pragma unroll
    for (int rr = 0; rr < 4; ++rr)
      pmax[rr] = fmaxf(pmax[rr], __shfl_xor(pmax[rr], mask, 64));
  if (lr == 0)
#pragma unroll
    for (int rr = 0; rr < 4; ++rr) rowmax[g * 4 + rr][w] = pmax[rr];
  __syncthreads();

  // ---- softmax: row r handled by 32 lanes (j), 8 chunks of 8 each ----
  const int r = t >> 5, j = t & 31;
  float mx = rowmax[r][0];
#pragma unroll
  for (int ww = 1; ww < 8; ++ww) mx = fmaxf(mx, rowmax[r][ww]);

  float sum = 0.f;
  for (int i = 0; i < 8; ++i) {
    const int c = j + (i << 5);
    const int pc = c ^ (r & 7);
    const bf16x8 v = *(const bf16x8*)&S[r * SSEQ + pc * 8];
#pragma unroll
    for (int e = 0; e < 8; ++e) sum += __expf(b2f(v[e]) - mx);
  }
#pragma unroll
  for (int mask = 1; mask < 32; mask <<= 1) sum += __shfl_xor(sum, mask, 64);
  const float inv = 1.f / sum;

  float* arow = attnO + ((size_t)bh * SSEQ + q0 + r) * SSEQ;
  for (int i = 0; i < 8; ++i) {
    const int c = j + (i << 5);
    const int pc = c ^ (r & 7);
    const bf16x8 v = *(const bf16x8*)&S[r * SSEQ + pc * 8];
    bf16x8 p;
    float4 w0, w1;
    {
      const float p0 = __expf(b2f(v[0]) - mx) * inv;
      const float p1 = __expf(b2f(v[1]) - mx) * inv;
      const float p2 = __expf(b2f(v[2]) - mx) * inv;
      const float p3 = __expf(b2f(v[3]) - mx) * inv;
      w0.x = p0; w0.y = p1; w0.z = p2; w0.w = p3;
      p[0] = f2b(p0); p[1] = f2b(p1); p[2] = f2b(p2); p[3] = f2b(p3);
      const float p4 = __expf(b2f(v[4]) - mx) * inv;
      const float p5 = __expf(b2f(v[5]) - mx) * inv;
      const float p6 = __expf(b2f(v[6]) - mx) * inv;
      const float p7 = __expf(b2f(v[7]) - mx) * inv;
      w1.x = p4; w1.y = p5; w1.z = p6; w1.w = p7;
      p[4] = f2b(p4); p[5] = f2b(p5); p[6] = f2b(p6); p[7] = f2b(p7);
    }
    *(float4*)(arow + (size_t)c * 8) = w0;
    *(float4*)(arow + (size_t)c * 8 + 4) = w1;
    *(bf16x8*)&S[r * SSEQ + pc * 8] = p;          // for PV
  }
  __syncthreads();

  // ---- PV: wave w -> d-tile d0=(w&3)*16, K-half kh=w>>2 (1024 each);
  //      4 K-steps batched per iter for load MLP ----
  const short* Vh = Vt + (size_t)bh * HDIM * SSEQ;
  const int d0 = (w & 3) * 16;
  const int kh = w >> 2;
  f32x4 acc;
  acc[0] = 0.f; acc[1] = 0.f; acc[2] = 0.f; acc[3] = 0.f;
  const int sbeg = kh * (SSEQ / 2);
  for (int s0 = sbeg; s0 < sbeg + SSEQ / 2; s0 += 128) {
    bf16x8 ap[4], bv[4];
#pragma unroll
    for (int u = 0; u < 4; ++u) {
      const int ss = s0 + u * 32;
      const int pc = ((ss >> 3) + g) ^ (lr & 7);
      ap[u] = *(const bf16x8*)&S[lr * SSEQ + pc * 8];
      bv[u] = *(const bf16x8*)&Vh[(size_t)(d0 + lr) * SSEQ + ss + g * 8];
    }
#pragma unroll
    for (int u = 0; u < 4; ++u)
      acc = __builtin_amdgcn_mfma_f32_16x16x32_bf16(ap[u], bv[u], acc, 0, 0, 0);
  }
  if (kh == 1) red[(w & 3) * 64 + l] = acc;
  __syncthreads();
  if (kh == 0) {
    const f32x4 o = red[(w & 3) * 64 + l];
    acc[0] += o[0]; acc[1] += o[1]; acc[2] += o[2]; acc[3] += o[3];
#pragma unroll
    for (int rr = 0; rr < 4; ++rr) {
      const int qr = q0 + g * 4 + rr;
      ctx[((size_t)b * SSEQ + qr) * D_MODEL + h * HDIM + d0 + lr] =
          f2b(acc[rr]);
    }
  }
}

// ---------------------------------------------------------------------------
extern "C" void kernel_launch(void* const* d_in, const int* in_sizes, int n_in,
                              void* d_out, int out_size, void* d_ws,
                              size_t ws_size, hipStream_t stream) {
  const float* qf  = (const float*)d_in[0];
  const float* kf  = (const float*)d_in[1];
  const float* vf  = (const float*)d_in[2];
  const float* wqf = (const float*)d_in[3];
  const float* wkf = (const float*)d_in[4];
  const float* wvf = (const float*)d_in[5];
  const float* wof = (const float*)d_in[6];

  float* out  = (float*)d_out;                       // [2,2048,1024]
  float* attn = out + (size_t)BB * SSEQ * D_MODEL;   // [2,16,2048,2048]

  const size_t NTOK = (size_t)BB * SSEQ;             // 4096
  const size_t XN = NTOK * D_MODEL;                  // 4M elements
  const size_t WN = (size_t)D_MODEL * D_MODEL;       // 1M elements

  short* qb  = (short*)d_ws;       // bf16 copies of inputs
  short* kb  = qb + XN;
  short* vb  = kb + XN;
  short* wqb = vb + XN;
  short* wkb = wqb + WN;
  short* wvb = wkb + WN;
  short* wob = wvb + WN;
  short* Qb  = wob + WN;           // projection results
  short* Kb  = Qb + XN;
  short* Vb  = Kb + XN;
  short* Vt  = Vb + XN;
  short* ctx = Vt + XN;            // total 72 MB

  // 0) fp32 -> bf16 conversions
  k_cvt<<<512, 256, 0, stream>>>(qf, qb, (int)(XN / 4));
  k_cvt<<<512, 256, 0, stream>>>(kf, kb, (int)(XN / 4));
  k_cvt<<<512, 256, 0, stream>>>(vf, vb, (int)(XN / 4));
  k_cvt<<<256, 256, 0, stream>>>(wqf, wqb, (int)(WN / 4));
  k_cvt<<<256, 256, 0, stream>>>(wkf, wkb, (int)(WN / 4));
  k_cvt<<<256, 256, 0, stream>>>(wvf, wvb, (int)(WN / 4));
  k_cvt<<<256, 256, 0, stream>>>(wof, wob, (int)(WN / 4));

  // 1) Q/K/V projections: x @ W^T
  k_gemm_qkv<<<dim3(D_MODEL / 128, NTOK / 128, 3), 256, 0, stream>>>(
      qb, kb, vb, wqb, wkb, wvb, Qb, Kb, Vb);
  // 2) V -> Vt[b,h,d,s]
  k_transpose_v<<<dim3(BB * NHEADS, SSEQ / 64), 256, 0, stream>>>(Vb, Vt);
  // 3) fused attention (+ attn_weights output, fp32)
  k_attn<<<4096, 512, 0, stream>>>(Qb, Kb, Vt, attn, ctx);
  // 4) output projection: ctx @ Wo^T (fp32 out)
  k_gemm_f32out<<<dim3(D_MODEL / 128, NTOK / 128), 256, 0, stream>>>(
      ctx, wob, out, D_MODEL, D_MODEL);
}